// Round 12
// baseline (451.276 us; speedup 1.0000x reference)
//
#include <hip/hip_runtime.h>
#include <hip/hip_fp16.h>
#include <math.h>

#define N_NODES 100000
#define N_EDGES 1600000
#define NEG_SLOPE 0.2f
#define EPS 1e-16f

__device__ __forceinline__ float lrelu(float v) { return v > 0.f ? v : NEG_SLOPE * v; }

// load 4 halfs -> float4 (single 8B load)
__device__ __forceinline__ float4 ld4h(const __half* p) {
    uint2 r = *(const uint2*)p;
    __half2 h0 = *reinterpret_cast<const __half2*>(&r.x);
    __half2 h1 = *reinterpret_cast<const __half2*>(&r.y);
    float2 f0 = __half22float2(h0), f1 = __half22float2(h1);
    return make_float4(f0.x, f0.y, f1.x, f1.y);
}

// ---------------------------------------------------------------- zero deg
__global__ void k_zero_deg(int* __restrict__ deg) {
    int i = blockIdx.x * blockDim.x + threadIdx.x;
    if (i < N_NODES) deg[i] = 0;
}

// ---------------------------------------------------------------- XCD-partitioned histogram of dst
#define HISTX_BLOCKS 2048
__global__ void k_hist_x(const int* __restrict__ ei, int* __restrict__ deg) {
    const int step = (N_NODES + 7) / 8;
    int xcd = blockIdx.x & 7;
    int lo = xcd * step;
    int hi = (lo + step < N_NODES) ? lo + step : N_NODES;
    int gid = (blockIdx.x >> 3) * blockDim.x + threadIdx.x;
    const int stride = (HISTX_BLOCKS >> 3) * 256;
    for (int e = gid; e < N_EDGES; e += stride) {
        int dst = ei[N_EDGES + e];
        if (dst >= lo && dst < hi) atomicAdd(&deg[dst], 1);
    }
}

// ---------------------------------------------------------------- scan level 1
__global__ void k_scan_part(const int* __restrict__ deg, int* __restrict__ loc,
                            int* __restrict__ partial) {
    __shared__ int tmp[256];
    int i = blockIdx.x * 256 + threadIdx.x;
    int v = (i < N_NODES) ? deg[i] : 0;
    tmp[threadIdx.x] = v;
    __syncthreads();
    for (int off = 1; off < 256; off <<= 1) {
        int t = (threadIdx.x >= off) ? tmp[threadIdx.x - off] : 0;
        __syncthreads();
        tmp[threadIdx.x] += t;
        __syncthreads();
    }
    if (i < N_NODES) loc[i] = tmp[threadIdx.x] - v;   // exclusive
    if (threadIdx.x == 255) partial[blockIdx.x] = tmp[255];
}

// ---------------------------------------------------------------- scan level 2 (nb <= 512)
__global__ void k_scan_tot(int* __restrict__ partial, int nb) {
    __shared__ int tmp[512];
    int v = (threadIdx.x < nb) ? partial[threadIdx.x] : 0;
    tmp[threadIdx.x] = v;
    __syncthreads();
    for (int off = 1; off < 512; off <<= 1) {
        int t = (threadIdx.x >= off) ? tmp[threadIdx.x - off] : 0;
        __syncthreads();
        tmp[threadIdx.x] += t;
        __syncthreads();
    }
    if (threadIdx.x < nb) partial[threadIdx.x] = tmp[threadIdx.x] - v;  // exclusive
}

// ---------------------------------------------------------------- scan level 3 + cursor init
__global__ void k_scan_add(const int* __restrict__ loc, const int* __restrict__ partial,
                           int* __restrict__ rowptr, int* __restrict__ cursor) {
    int i = blockIdx.x * blockDim.x + threadIdx.x;
    if (i < N_NODES) {
        int r = loc[i] + partial[i >> 8];
        rowptr[i] = r;
        cursor[i] = r;
    }
}

// ---------------------------------------------------------------- XCD-partitioned scatter
#define SCATX_BLOCKS 2048
__global__ void k_scatter_x(const int* __restrict__ ei, int* __restrict__ cursor,
                            int* __restrict__ csr_src) {
    const int step = (N_NODES + 7) / 8;
    int xcd = blockIdx.x & 7;
    int lo = xcd * step;
    int hi = (lo + step < N_NODES) ? lo + step : N_NODES;
    int gid = (blockIdx.x >> 3) * blockDim.x + threadIdx.x;
    const int stride = (SCATX_BLOCKS >> 3) * 256;
    for (int e = gid; e < N_EDGES; e += stride) {
        int dst = ei[N_EDGES + e];
        if (dst >= lo && dst < hi) {
            int pos = atomicAdd(&cursor[dst], 1);
            csr_src[pos] = ei[e];
        }
    }
}

// ---------------------------------------------------------------- K-Q: qs[h] = W1_h^T a_src_h, qd[h] = W1_h^T a_dst_h  (24 floats)
__global__ void k_q(const float* __restrict__ w1, const float* __restrict__ as1,
                    const float* __restrict__ ad1, float* __restrict__ qv) {
    int t = threadIdx.x;
    if (t >= 24) return;
    int c = t % 3, h = (t / 3) % 4, side = t / 12;
    const float* att = side ? ad1 : as1;
    float acc = 0.f;
    for (int cc = 0; cc < 32; cc++)
        acc += att[h * 32 + cc] * w1[(h * 32 + cc) * 3 + c];
    qv[t] = acc;
}

// ---------------------------------------------------------------- K-NODE1: a1d = x.qd ; p1[n] = {a1s[4], x0,x1,x2,1} (32B row)
__global__ void k_node1(const float* __restrict__ x, const float* __restrict__ qv,
                        float* __restrict__ a1d, float* __restrict__ p1) {
    int n = blockIdx.x * blockDim.x + threadIdx.x;
    if (n >= N_NODES) return;
    float x0 = x[n * 3], x1 = x[n * 3 + 1], x2 = x[n * 3 + 2];
    float4 s, d;
    s.x = x0 * qv[0]  + x1 * qv[1]  + x2 * qv[2];
    s.y = x0 * qv[3]  + x1 * qv[4]  + x2 * qv[5];
    s.z = x0 * qv[6]  + x1 * qv[7]  + x2 * qv[8];
    s.w = x0 * qv[9]  + x1 * qv[10] + x2 * qv[11];
    d.x = x0 * qv[12] + x1 * qv[13] + x2 * qv[14];
    d.y = x0 * qv[15] + x1 * qv[16] + x2 * qv[17];
    d.z = x0 * qv[18] + x1 * qv[19] + x2 * qv[20];
    d.w = x0 * qv[21] + x1 * qv[22] + x2 * qv[23];
    ((float4*)a1d)[n] = d;
    ((float4*)p1)[n * 2]     = s;
    float4 xx; xx.x = x0; xx.y = x1; xx.z = x2; xx.w = 1.f;
    ((float4*)p1)[n * 2 + 1] = xx;
}

// ---------------------------------------------------------------- K-GAT1: linearity trick, w2 in registers, packed p1 gathers
// h2 emitted as fp16 (row = 64B = 1 line)
#define G1_BLOCKS ((N_NODES + 63) / 64)
__global__ void k_gat1(const int* __restrict__ rowptr, const int* __restrict__ deg,
                       const int* __restrict__ csr_src,
                       const float* __restrict__ p1, const float* __restrict__ w1,
                       const float* __restrict__ a1d,
                       const float* __restrict__ b1, const float* __restrict__ w2,
                       const float* __restrict__ as2, const float* __restrict__ ad2,
                       __half* __restrict__ h2, float* __restrict__ a2s, float* __restrict__ a2d) {
    __shared__ float sm[64][16];      // per-node: 4 heads x {s0,s1,s2,den}
    __shared__ float f1s[4][128];
    int tid = threadIdx.x;
    int wave = tid >> 6, lane = tid & 63;
    int o = lane & 31, half = lane >> 5;
    int k0 = half * 64;

    // per-lane w2 column: w2[o][k0..k0+63] in 64 VGPRs
    float w2r[64];
    {
        const float4* wp = (const float4*)(w2 + o * 128 + k0);
        #pragma unroll
        for (int q = 0; q < 16; q++) {
            float4 t = wp[q];
            w2r[q * 4 + 0] = t.x; w2r[q * 4 + 1] = t.y;
            w2r[q * 4 + 2] = t.z; w2r[q * 4 + 3] = t.w;
        }
    }

    // ---- phase A: node = block*64 + wave*16 + (lane>>2), head = lane&3
    int nl = wave * 16 + (lane >> 2);
    int h  = lane & 3;
    int n  = blockIdx.x * 64 + nl;
    if (n < N_NODES) {
        float adh = a1d[n * 4 + h];
        int beg = rowptr[n], cnt = deg[n];
        float s0a = 0.f, s1a = 0.f, s2a = 0.f, da = 0.f;
        int t = 0;
        for (; t + 4 <= cnt; t += 4) {
            int s0 = csr_src[beg + t + 0], s1 = csr_src[beg + t + 1];
            int s2 = csr_src[beg + t + 2], s3 = csr_src[beg + t + 3];
            float4 A0 = ((const float4*)p1)[s0 * 2], X0 = ((const float4*)p1)[s0 * 2 + 1];
            float4 A1 = ((const float4*)p1)[s1 * 2], X1 = ((const float4*)p1)[s1 * 2 + 1];
            float4 A2 = ((const float4*)p1)[s2 * 2], X2 = ((const float4*)p1)[s2 * 2 + 1];
            float4 A3 = ((const float4*)p1)[s3 * 2], X3 = ((const float4*)p1)[s3 * 2 + 1];
            float l0 = h == 0 ? A0.x : h == 1 ? A0.y : h == 2 ? A0.z : A0.w;
            float l1 = h == 0 ? A1.x : h == 1 ? A1.y : h == 2 ? A1.z : A1.w;
            float l2 = h == 0 ? A2.x : h == 1 ? A2.y : h == 2 ? A2.z : A2.w;
            float l3 = h == 0 ? A3.x : h == 1 ? A3.y : h == 2 ? A3.z : A3.w;
            float e0 = __expf(lrelu(l0 + adh));
            float e1 = __expf(lrelu(l1 + adh));
            float e2 = __expf(lrelu(l2 + adh));
            float e3 = __expf(lrelu(l3 + adh));
            s0a += e0 * X0.x + e1 * X1.x + e2 * X2.x + e3 * X3.x;
            s1a += e0 * X0.y + e1 * X1.y + e2 * X2.y + e3 * X3.y;
            s2a += e0 * X0.z + e1 * X1.z + e2 * X2.z + e3 * X3.z;
            da  += e0 + e1 + e2 + e3;
        }
        for (; t < cnt; t++) {
            int s = csr_src[beg + t];
            float4 A = ((const float4*)p1)[s * 2], X = ((const float4*)p1)[s * 2 + 1];
            float l = h == 0 ? A.x : h == 1 ? A.y : h == 2 ? A.z : A.w;
            float ex = __expf(lrelu(l + adh));
            s0a += ex * X.x;
            s1a += ex * X.y;
            s2a += ex * X.z;
            da  += ex;
        }
        float4 r; r.x = s0a; r.y = s1a; r.z = s2a; r.w = da;
        *(float4*)&sm[nl][h * 4] = r;
    }
    // same-wave LDS write->read below: no barrier needed

    // ---- phase B: wave processes its own 16 nodes
    int j = lane, j2 = lane + 64;
    int h0 = j >> 5;
    float wa0 = w1[j * 3], wa1 = w1[j * 3 + 1], wa2 = w1[j * 3 + 2];
    float wb0 = w1[j2 * 3], wb1 = w1[j2 * 3 + 1], wb2 = w1[j2 * 3 + 2];
    float b1j = b1[j], b1j2 = b1[j2];
    float as2o = as2[o], ad2o = ad2[o];
    const float* f = f1s[wave];

    #pragma unroll 1
    for (int i = 0; i < 16; i++) {
        int n2 = blockIdx.x * 64 + wave * 16 + i;
        if (n2 >= N_NODES) break;
        const float* S = sm[wave * 16 + i];
        float v0 = (wa0 * S[h0 * 4] + wa1 * S[h0 * 4 + 1] + wa2 * S[h0 * 4 + 2])
                   / (S[h0 * 4 + 3] + EPS) + b1j;
        float v1 = (wb0 * S[(2 + h0) * 4] + wb1 * S[(2 + h0) * 4 + 1] + wb2 * S[(2 + h0) * 4 + 2])
                   / (S[(2 + h0) * 4 + 3] + EPS) + b1j2;
        f1s[wave][j]  = v0 > 0.f ? v0 : expm1f(v0);
        f1s[wave][j2] = v1 > 0.f ? v1 : expm1f(v1);
        float acc = 0.f;
        #pragma unroll
        for (int t = 0; t < 64; t++)
            acc += f[k0 + t] * w2r[t];
        acc += __shfl_down(acc, 32);
        if (half == 0) {
            h2[n2 * 32 + o] = __float2half(acc);
            float ps = acc * as2o, pd = acc * ad2o;
            #pragma unroll
            for (int off = 16; off; off >>= 1) {
                ps += __shfl_xor(ps, off);
                pd += __shfl_xor(pd, off);
            }
            if (o == 0) { a2s[n2] = ps; a2d[n2] = pd; }
        }
    }
}

// ---------------------------------------------------------------- K-GAT2: full wave per node; fp16 h2 gathers (1 line/edge)
#define G2_BLOCKS 4096
__global__ void k_gat2(const int* __restrict__ rowptr, const int* __restrict__ deg,
                       const int* __restrict__ csr_src,
                       const __half* __restrict__ h2, const float* __restrict__ a2s,
                       const float* __restrict__ a2d, const float* __restrict__ b2,
                       const float* __restrict__ mw1, const float* __restrict__ mb1,
                       __half* __restrict__ u, __half* __restrict__ v) {
    int tid = threadIdx.x;
    int lane = tid & 63;
    int c = lane & 31, half = lane >> 5;
    float W[32];
    const float4* ap = (const float4*)(mw1 + c * 64 + half * 32);
    #pragma unroll
    for (int q = 0; q < 8; q++) {
        float4 t = ap[q];
        W[q * 4 + 0] = t.x; W[q * 4 + 1] = t.y; W[q * 4 + 2] = t.z; W[q * 4 + 3] = t.w;
    }
    float bias = half ? 0.f : mb1[c];
    float b2c = b2[c];
    __half* outp = half ? v : u;
    int wid = blockIdx.x * 4 + (tid >> 6);
    const int stride = G2_BLOCKS * 4;
    for (int n = wid; n < N_NODES; n += stride) {
        float ad = a2d[n];
        int beg = rowptr[n], cnt = deg[n];
        float acc = 0.f, den = 0.f;
        // this half handles edge indices half, half+2, ... (2 per iter)
        int t = half;
        for (; t + 2 < cnt; t += 4) {
            int s0 = csr_src[beg + t], s1 = csr_src[beg + t + 2];
            float l0 = a2s[s0], l1 = a2s[s1];
            float g0 = __half2float(h2[s0 * 32 + c]);
            float g1 = __half2float(h2[s1 * 32 + c]);
            float e0 = __expf(lrelu(l0 + ad));
            float e1 = __expf(lrelu(l1 + ad));
            acc += e0 * g0 + e1 * g1;
            den += e0 + e1;
        }
        if (t < cnt) {
            int s = csr_src[beg + t];
            float ex = __expf(lrelu(a2s[s] + ad));
            acc += ex * __half2float(h2[s * 32 + c]);
            den += ex;
        }
        acc += __shfl_xor(acc, 32);
        den += __shfl_xor(den, 32);
        float hfc = acc / (den + EPS) + b2c;
        float r = bias;
        #pragma unroll
        for (int k = 0; k < 32; k++)
            r += W[k] * __shfl(hfc, k, 32);
        outp[n * 32 + c] = __float2half(r);
    }
}

// ---------------------------------------------------------------- K-MLP: 8 lanes/edge, 4 edges/iter, fp16 u/v rows (1 line each)
#define MLP_BLOCKS 4096
__global__ void k_mlp(const int* __restrict__ ei, const __half* __restrict__ u,
                      const __half* __restrict__ v, const float* __restrict__ mw2,
                      const float* __restrict__ mb2, float* __restrict__ out) {
    int tid = threadIdx.x;
    int q = tid & 7;
    float4 w2q = ((const float4*)mw2)[q];
    float mb20 = mb2[0];
    int g = blockIdx.x * 32 + (tid >> 3);
    const int stride = MLP_BLOCKS * 32 * 4;
    for (int e = g * 4; e < N_EDGES; e += stride) {
        int eb = e;
        int e1 = (eb + 1 < N_EDGES) ? eb + 1 : eb;
        int e2 = (eb + 2 < N_EDGES) ? eb + 2 : eb;
        int e3 = (eb + 3 < N_EDGES) ? eb + 3 : eb;
        int sa = ei[eb], da = ei[N_EDGES + eb];
        int sb = ei[e1], db = ei[N_EDGES + e1];
        int sc = ei[e2], dc = ei[N_EDGES + e2];
        int sd = ei[e3], dd = ei[N_EDGES + e3];
        float4 ua = ld4h(u + sa * 32 + q * 4);
        float4 va = ld4h(v + da * 32 + q * 4);
        float4 ub = ld4h(u + sb * 32 + q * 4);
        float4 vb = ld4h(v + db * 32 + q * 4);
        float4 uc = ld4h(u + sc * 32 + q * 4);
        float4 vc = ld4h(v + dc * 32 + q * 4);
        float4 ud = ld4h(u + sd * 32 + q * 4);
        float4 vd = ld4h(v + dd * 32 + q * 4);
        float s0 = fmaxf(ua.x + va.x, 0.f) * w2q.x + fmaxf(ua.y + va.y, 0.f) * w2q.y
                 + fmaxf(ua.z + va.z, 0.f) * w2q.z + fmaxf(ua.w + va.w, 0.f) * w2q.w;
        float s1 = fmaxf(ub.x + vb.x, 0.f) * w2q.x + fmaxf(ub.y + vb.y, 0.f) * w2q.y
                 + fmaxf(ub.z + vb.z, 0.f) * w2q.z + fmaxf(ub.w + vb.w, 0.f) * w2q.w;
        float s2 = fmaxf(uc.x + vc.x, 0.f) * w2q.x + fmaxf(uc.y + vc.y, 0.f) * w2q.y
                 + fmaxf(uc.z + vc.z, 0.f) * w2q.z + fmaxf(uc.w + vc.w, 0.f) * w2q.w;
        float s3 = fmaxf(ud.x + vd.x, 0.f) * w2q.x + fmaxf(ud.y + vd.y, 0.f) * w2q.y
                 + fmaxf(ud.z + vd.z, 0.f) * w2q.z + fmaxf(ud.w + vd.w, 0.f) * w2q.w;
        s0 += __shfl_xor(s0, 1, 8); s0 += __shfl_xor(s0, 2, 8); s0 += __shfl_xor(s0, 4, 8);
        s1 += __shfl_xor(s1, 1, 8); s1 += __shfl_xor(s1, 2, 8); s1 += __shfl_xor(s1, 4, 8);
        s2 += __shfl_xor(s2, 1, 8); s2 += __shfl_xor(s2, 2, 8); s2 += __shfl_xor(s2, 4, 8);
        s3 += __shfl_xor(s3, 1, 8); s3 += __shfl_xor(s3, 2, 8); s3 += __shfl_xor(s3, 4, 8);
        if (q == 0) {
            out[eb] = fmaxf(s0 + mb20, 0.f);
            if (eb + 1 < N_EDGES) out[eb + 1] = fmaxf(s1 + mb20, 0.f);
            if (eb + 2 < N_EDGES) out[eb + 2] = fmaxf(s2 + mb20, 0.f);
            if (eb + 3 < N_EDGES) out[eb + 3] = fmaxf(s3 + mb20, 0.f);
        }
    }
}

// ---------------------------------------------------------------- launch
extern "C" void kernel_launch(void* const* d_in, const int* in_sizes, int n_in,
                              void* d_out, int out_size, void* d_ws, size_t ws_size,
                              hipStream_t stream) {
    const float* x    = (const float*)d_in[0];
    const int*   ei   = (const int*)d_in[1];
    const float* w1   = (const float*)d_in[2];
    const float* as1  = (const float*)d_in[3];
    const float* ad1  = (const float*)d_in[4];
    const float* b1   = (const float*)d_in[5];
    const float* w2   = (const float*)d_in[6];
    const float* as2  = (const float*)d_in[7];
    const float* ad2  = (const float*)d_in[8];
    const float* b2   = (const float*)d_in[9];
    const float* mw1  = (const float*)d_in[10];
    const float* mb1  = (const float*)d_in[11];
    const float* mw2  = (const float*)d_in[12];
    const float* mb2  = (const float*)d_in[13];
    float* out = (float*)d_out;

    const int N = N_NODES, E = N_EDGES;
    // byte-offset workspace layout; p1/h2/u/v are 64B aligned (verified offsets)
    char* base   = (char*)d_ws;
    int* deg     = (int*)(base);                      // N*4       @0
    int* rowptr  = (int*)(base + 400000);             // N*4
    int* cursor  = (int*)(base + 800000);             // N*4
    int* loc     = (int*)(base + 1200000);            // N*4
    int* partial = (int*)(base + 1600000);            // 2048
    int* csr_src = (int*)(base + 1602048);            // E*4
    float* p1    = (float*)(base + 8002048);          // 8N*4   (%64==0)
    float* a1d   = (float*)(base + 11202048);         // 4N*4
    __half* h2   = (__half*)(base + 12802048);        // 32N*2  (%64==0)
    float* a2s   = (float*)(base + 19202048);         // N*4
    float* a2d   = (float*)(base + 19602048);         // N*4
    __half* u    = (__half*)(base + 20002048);        // 32N*2  (%64==0)
    __half* v    = (__half*)(base + 26402048);        // 32N*2
    float* qv    = (float*)(base + 32802048);         // 24

    const int nb = (N + 255) / 256;

    k_zero_deg<<<nb, 256, 0, stream>>>(deg);
    k_hist_x<<<HISTX_BLOCKS, 256, 0, stream>>>(ei, deg);
    k_scan_part<<<nb, 256, 0, stream>>>(deg, loc, partial);
    k_scan_tot<<<1, 512, 0, stream>>>(partial, nb);
    k_scan_add<<<nb, 256, 0, stream>>>(loc, partial, rowptr, cursor);

    k_scatter_x<<<SCATX_BLOCKS, 256, 0, stream>>>(ei, cursor, csr_src);

    k_q<<<1, 32, 0, stream>>>(w1, as1, ad1, qv);
    k_node1<<<nb, 256, 0, stream>>>(x, qv, a1d, p1);

    k_gat1<<<G1_BLOCKS, 256, 0, stream>>>(rowptr, deg, csr_src, p1, w1, a1d,
                                          b1, w2, as2, ad2, h2, a2s, a2d);

    k_gat2<<<G2_BLOCKS, 256, 0, stream>>>(rowptr, deg, csr_src, h2, a2s, a2d, b2,
                                          mw1, mb1, u, v);

    k_mlp<<<MLP_BLOCKS, 256, 0, stream>>>(ei, u, v, mw2, mb2, out);
}

// Round 14
// 450.124 us; speedup vs baseline: 1.0026x; 1.0026x over previous
//
#include <hip/hip_runtime.h>
#include <hip/hip_fp16.h>
#include <math.h>

#define N_NODES 100000
#define N_EDGES 1600000
#define NEG_SLOPE 0.2f
#define EPS 1e-16f

__device__ __forceinline__ float lrelu(float v) { return v > 0.f ? v : NEG_SLOPE * v; }

// load 4 halfs -> float4 (single 8B load)
__device__ __forceinline__ float4 ld4h(const __half* p) {
    uint2 r = *(const uint2*)p;
    __half2 h0 = *reinterpret_cast<const __half2*>(&r.x);
    __half2 h1 = *reinterpret_cast<const __half2*>(&r.y);
    float2 f0 = __half22float2(h0), f1 = __half22float2(h1);
    return make_float4(f0.x, f0.y, f1.x, f1.y);
}

// ---------------------------------------------------------------- zero deg
__global__ void k_zero_deg(int* __restrict__ deg) {
    int i = blockIdx.x * blockDim.x + threadIdx.x;
    if (i < N_NODES) deg[i] = 0;
}

// ---------------------------------------------------------------- XCD-partitioned histogram of dst
#define HISTX_BLOCKS 2048
__global__ void k_hist_x(const int* __restrict__ ei, int* __restrict__ deg) {
    const int step = (N_NODES + 7) / 8;
    int xcd = blockIdx.x & 7;
    int lo = xcd * step;
    int hi = (lo + step < N_NODES) ? lo + step : N_NODES;
    int gid = (blockIdx.x >> 3) * blockDim.x + threadIdx.x;
    const int stride = (HISTX_BLOCKS >> 3) * 256;
    for (int e = gid; e < N_EDGES; e += stride) {
        int dst = ei[N_EDGES + e];
        if (dst >= lo && dst < hi) atomicAdd(&deg[dst], 1);
    }
}

// ---------------------------------------------------------------- scan level 1
__global__ void k_scan_part(const int* __restrict__ deg, int* __restrict__ loc,
                            int* __restrict__ partial) {
    __shared__ int tmp[256];
    int i = blockIdx.x * 256 + threadIdx.x;
    int v = (i < N_NODES) ? deg[i] : 0;
    tmp[threadIdx.x] = v;
    __syncthreads();
    for (int off = 1; off < 256; off <<= 1) {
        int t = (threadIdx.x >= off) ? tmp[threadIdx.x - off] : 0;
        __syncthreads();
        tmp[threadIdx.x] += t;
        __syncthreads();
    }
    if (i < N_NODES) loc[i] = tmp[threadIdx.x] - v;   // exclusive
    if (threadIdx.x == 255) partial[blockIdx.x] = tmp[255];
}

// ---------------------------------------------------------------- scan level 2 (nb <= 512)
__global__ void k_scan_tot(int* __restrict__ partial, int nb) {
    __shared__ int tmp[512];
    int v = (threadIdx.x < nb) ? partial[threadIdx.x] : 0;
    tmp[threadIdx.x] = v;
    __syncthreads();
    for (int off = 1; off < 512; off <<= 1) {
        int t = (threadIdx.x >= off) ? tmp[threadIdx.x - off] : 0;
        __syncthreads();
        tmp[threadIdx.x] += t;
        __syncthreads();
    }
    if (threadIdx.x < nb) partial[threadIdx.x] = tmp[threadIdx.x] - v;  // exclusive
}

// ---------------------------------------------------------------- scan level 3 + cursor init
__global__ void k_scan_add(const int* __restrict__ loc, const int* __restrict__ partial,
                           int* __restrict__ rowptr, int* __restrict__ cursor) {
    int i = blockIdx.x * blockDim.x + threadIdx.x;
    if (i < N_NODES) {
        int r = loc[i] + partial[i >> 8];
        rowptr[i] = r;
        cursor[i] = r;
    }
}

// ---------------------------------------------------------------- XCD-partitioned scatter
#define SCATX_BLOCKS 2048
__global__ void k_scatter_x(const int* __restrict__ ei, int* __restrict__ cursor,
                            int* __restrict__ csr_src) {
    const int step = (N_NODES + 7) / 8;
    int xcd = blockIdx.x & 7;
    int lo = xcd * step;
    int hi = (lo + step < N_NODES) ? lo + step : N_NODES;
    int gid = (blockIdx.x >> 3) * blockDim.x + threadIdx.x;
    const int stride = (SCATX_BLOCKS >> 3) * 256;
    for (int e = gid; e < N_EDGES; e += stride) {
        int dst = ei[N_EDGES + e];
        if (dst >= lo && dst < hi) {
            int pos = atomicAdd(&cursor[dst], 1);
            csr_src[pos] = ei[e];
        }
    }
}

// ---------------------------------------------------------------- K-Q: qs[h] = W1_h^T a_src_h, qd[h] = W1_h^T a_dst_h  (24 floats)
__global__ void k_q(const float* __restrict__ w1, const float* __restrict__ as1,
                    const float* __restrict__ ad1, float* __restrict__ qv) {
    int t = threadIdx.x;
    if (t >= 24) return;
    int c = t % 3, h = (t / 3) % 4, side = t / 12;
    const float* att = side ? ad1 : as1;
    float acc = 0.f;
    for (int cc = 0; cc < 32; cc++)
        acc += att[h * 32 + cc] * w1[(h * 32 + cc) * 3 + c];
    qv[t] = acc;
}

// ---------------------------------------------------------------- K-NODE1: a1d = x.qd ; p1[n] = {a1s[4], x0,x1,x2,1} (32B row)
__global__ void k_node1(const float* __restrict__ x, const float* __restrict__ qv,
                        float* __restrict__ a1d, float* __restrict__ p1) {
    int n = blockIdx.x * blockDim.x + threadIdx.x;
    if (n >= N_NODES) return;
    float x0 = x[n * 3], x1 = x[n * 3 + 1], x2 = x[n * 3 + 2];
    float4 s, d;
    s.x = x0 * qv[0]  + x1 * qv[1]  + x2 * qv[2];
    s.y = x0 * qv[3]  + x1 * qv[4]  + x2 * qv[5];
    s.z = x0 * qv[6]  + x1 * qv[7]  + x2 * qv[8];
    s.w = x0 * qv[9]  + x1 * qv[10] + x2 * qv[11];
    d.x = x0 * qv[12] + x1 * qv[13] + x2 * qv[14];
    d.y = x0 * qv[15] + x1 * qv[16] + x2 * qv[17];
    d.z = x0 * qv[18] + x1 * qv[19] + x2 * qv[20];
    d.w = x0 * qv[21] + x1 * qv[22] + x2 * qv[23];
    ((float4*)a1d)[n] = d;
    ((float4*)p1)[n * 2]     = s;
    float4 xx; xx.x = x0; xx.y = x1; xx.z = x2; xx.w = 1.f;
    ((float4*)p1)[n * 2 + 1] = xx;
}

// ---------------------------------------------------------------- K-GAT1: linearity trick, w2 in registers, packed p1 gathers
#define G1_BLOCKS ((N_NODES + 63) / 64)
__global__ void k_gat1(const int* __restrict__ rowptr, const int* __restrict__ deg,
                       const int* __restrict__ csr_src,
                       const float* __restrict__ p1, const float* __restrict__ w1,
                       const float* __restrict__ a1d,
                       const float* __restrict__ b1, const float* __restrict__ w2,
                       const float* __restrict__ as2, const float* __restrict__ ad2,
                       float* __restrict__ h2, float* __restrict__ a2s, float* __restrict__ a2d) {
    __shared__ float sm[64][16];      // per-node: 4 heads x {s0,s1,s2,den}
    __shared__ float f1s[4][128];
    int tid = threadIdx.x;
    int wave = tid >> 6, lane = tid & 63;
    int o = lane & 31, half = lane >> 5;
    int k0 = half * 64;

    // per-lane w2 column: w2[o][k0..k0+63] in 64 VGPRs
    float w2r[64];
    {
        const float4* wp = (const float4*)(w2 + o * 128 + k0);
        #pragma unroll
        for (int q = 0; q < 16; q++) {
            float4 t = wp[q];
            w2r[q * 4 + 0] = t.x; w2r[q * 4 + 1] = t.y;
            w2r[q * 4 + 2] = t.z; w2r[q * 4 + 3] = t.w;
        }
    }

    // ---- phase A: node = block*64 + wave*16 + (lane>>2), head = lane&3
    int nl = wave * 16 + (lane >> 2);
    int h  = lane & 3;
    int n  = blockIdx.x * 64 + nl;
    if (n < N_NODES) {
        float adh = a1d[n * 4 + h];
        int beg = rowptr[n], cnt = deg[n];
        float s0a = 0.f, s1a = 0.f, s2a = 0.f, da = 0.f;
        int t = 0;
        for (; t + 4 <= cnt; t += 4) {
            int s0 = csr_src[beg + t + 0], s1 = csr_src[beg + t + 1];
            int s2 = csr_src[beg + t + 2], s3 = csr_src[beg + t + 3];
            float4 A0 = ((const float4*)p1)[s0 * 2], X0 = ((const float4*)p1)[s0 * 2 + 1];
            float4 A1 = ((const float4*)p1)[s1 * 2], X1 = ((const float4*)p1)[s1 * 2 + 1];
            float4 A2 = ((const float4*)p1)[s2 * 2], X2 = ((const float4*)p1)[s2 * 2 + 1];
            float4 A3 = ((const float4*)p1)[s3 * 2], X3 = ((const float4*)p1)[s3 * 2 + 1];
            float l0 = h == 0 ? A0.x : h == 1 ? A0.y : h == 2 ? A0.z : A0.w;
            float l1 = h == 0 ? A1.x : h == 1 ? A1.y : h == 2 ? A1.z : A1.w;
            float l2 = h == 0 ? A2.x : h == 1 ? A2.y : h == 2 ? A2.z : A2.w;
            float l3 = h == 0 ? A3.x : h == 1 ? A3.y : h == 2 ? A3.z : A3.w;
            float e0 = __expf(lrelu(l0 + adh));
            float e1 = __expf(lrelu(l1 + adh));
            float e2 = __expf(lrelu(l2 + adh));
            float e3 = __expf(lrelu(l3 + adh));
            s0a += e0 * X0.x + e1 * X1.x + e2 * X2.x + e3 * X3.x;
            s1a += e0 * X0.y + e1 * X1.y + e2 * X2.y + e3 * X3.y;
            s2a += e0 * X0.z + e1 * X1.z + e2 * X2.z + e3 * X3.z;
            da  += e0 + e1 + e2 + e3;
        }
        for (; t < cnt; t++) {
            int s = csr_src[beg + t];
            float4 A = ((const float4*)p1)[s * 2], X = ((const float4*)p1)[s * 2 + 1];
            float l = h == 0 ? A.x : h == 1 ? A.y : h == 2 ? A.z : A.w;
            float ex = __expf(lrelu(l + adh));
            s0a += ex * X.x;
            s1a += ex * X.y;
            s2a += ex * X.z;
            da  += ex;
        }
        float4 r; r.x = s0a; r.y = s1a; r.z = s2a; r.w = da;
        *(float4*)&sm[nl][h * 4] = r;
    }
    // same-wave LDS write->read below: no barrier needed

    // ---- phase B: wave processes its own 16 nodes
    int j = lane, j2 = lane + 64;
    int h0 = j >> 5;
    float wa0 = w1[j * 3], wa1 = w1[j * 3 + 1], wa2 = w1[j * 3 + 2];
    float wb0 = w1[j2 * 3], wb1 = w1[j2 * 3 + 1], wb2 = w1[j2 * 3 + 2];
    float b1j = b1[j], b1j2 = b1[j2];
    float as2o = as2[o], ad2o = ad2[o];
    const float* f = f1s[wave];

    #pragma unroll 1
    for (int i = 0; i < 16; i++) {
        int n2 = blockIdx.x * 64 + wave * 16 + i;
        if (n2 >= N_NODES) break;
        const float* S = sm[wave * 16 + i];
        float v0 = (wa0 * S[h0 * 4] + wa1 * S[h0 * 4 + 1] + wa2 * S[h0 * 4 + 2])
                   / (S[h0 * 4 + 3] + EPS) + b1j;
        float v1 = (wb0 * S[(2 + h0) * 4] + wb1 * S[(2 + h0) * 4 + 1] + wb2 * S[(2 + h0) * 4 + 2])
                   / (S[(2 + h0) * 4 + 3] + EPS) + b1j2;
        f1s[wave][j]  = v0 > 0.f ? v0 : expm1f(v0);
        f1s[wave][j2] = v1 > 0.f ? v1 : expm1f(v1);
        float acc = 0.f;
        #pragma unroll
        for (int t = 0; t < 64; t++)
            acc += f[k0 + t] * w2r[t];
        acc += __shfl_down(acc, 32);
        if (half == 0) {
            h2[n2 * 32 + o] = acc;
            float ps = acc * as2o, pd = acc * ad2o;
            #pragma unroll
            for (int off = 16; off; off >>= 1) {
                ps += __shfl_xor(ps, off);
                pd += __shfl_xor(pd, off);
            }
            if (o == 0) { a2s[n2] = ps; a2d[n2] = pd; }
        }
    }
}

// ---------------------------------------------------------------- K-GAT2: edge-broadcast form
// wave per node. Lane l owns edge (base+l): coalesced csr load, ONE gather +
// ONE expf per edge (not per channel). Then (idx,e) broadcast via shfl while
// 32 channels x 2 halves stream h2 rows. ~10 VMEM instrs/node vs ~24.
#define G2_BLOCKS 4096
__global__ void k_gat2(const int* __restrict__ rowptr, const int* __restrict__ deg,
                       const int* __restrict__ csr_src,
                       const float* __restrict__ h2, const float* __restrict__ a2s,
                       const float* __restrict__ a2d, const float* __restrict__ b2,
                       const float* __restrict__ mw1, const float* __restrict__ mb1,
                       __half* __restrict__ u, __half* __restrict__ v) {
    int tid = threadIdx.x;
    int lane = tid & 63;
    int c = lane & 31, half = lane >> 5;
    float W[32];
    const float4* ap = (const float4*)(mw1 + c * 64 + half * 32);
    #pragma unroll
    for (int q = 0; q < 8; q++) {
        float4 t = ap[q];
        W[q * 4 + 0] = t.x; W[q * 4 + 1] = t.y; W[q * 4 + 2] = t.z; W[q * 4 + 3] = t.w;
    }
    float bias = half ? 0.f : mb1[c];
    float b2c = b2[c];
    __half* outp = half ? v : u;
    int wid = blockIdx.x * 4 + (tid >> 6);
    const int stride = G2_BLOCKS * 4;
    for (int n = wid; n < N_NODES; n += stride) {
        float ad = a2d[n];
        int beg = rowptr[n], cnt = deg[n];
        float acc = 0.f, den = 0.f;
        for (int base = 0; base < cnt; base += 64) {
            int li = base + lane;
            int idx = (li < cnt) ? csr_src[beg + li] : 0;   // coalesced: 64 edges/VMEM
            float e = 0.f;
            if (li < cnt) e = __expf(lrelu(a2s[idx] + ad)); // 1 gather + 1 expf PER EDGE
            den += e;
            int m = cnt - base; if (m > 64) m = 64;
            // two edges in flight: half 0 -> even t, half 1 -> odd t
            for (int t = half; t < m; t += 2) {
                int   s  = __shfl(idx, t);
                float et = __shfl(e, t);
                acc += et * h2[s * 32 + c];
            }
        }
        acc += __shfl_xor(acc, 32);      // combine halves (channel c total)
        #pragma unroll
        for (int off = 32; off; off >>= 1) den += __shfl_xor(den, off);
        float hfc = acc / (den + EPS) + b2c;
        float r = bias;
        #pragma unroll
        for (int k = 0; k < 32; k++)
            r += W[k] * __shfl(hfc, k, 32);
        outp[n * 32 + c] = __float2half(r);
    }
}

// ---------------------------------------------------------------- K-MLP: 8 lanes/edge, 4 edges/iter, fp16 u/v rows (1 line each)
#define MLP_BLOCKS 4096
__global__ void k_mlp(const int* __restrict__ ei, const __half* __restrict__ u,
                      const __half* __restrict__ v, const float* __restrict__ mw2,
                      const float* __restrict__ mb2, float* __restrict__ out) {
    int tid = threadIdx.x;
    int q = tid & 7;
    float4 w2q = ((const float4*)mw2)[q];
    float mb20 = mb2[0];
    int g = blockIdx.x * 32 + (tid >> 3);
    const int stride = MLP_BLOCKS * 32 * 4;
    for (int e = g * 4; e < N_EDGES; e += stride) {
        int eb = e;
        int e1 = (eb + 1 < N_EDGES) ? eb + 1 : eb;
        int e2 = (eb + 2 < N_EDGES) ? eb + 2 : eb;
        int e3 = (eb + 3 < N_EDGES) ? eb + 3 : eb;
        int sa = ei[eb], da = ei[N_EDGES + eb];
        int sb = ei[e1], db = ei[N_EDGES + e1];
        int sc = ei[e2], dc = ei[N_EDGES + e2];
        int sd = ei[e3], dd = ei[N_EDGES + e3];
        float4 ua = ld4h(u + sa * 32 + q * 4);
        float4 va = ld4h(v + da * 32 + q * 4);
        float4 ub = ld4h(u + sb * 32 + q * 4);
        float4 vb = ld4h(v + db * 32 + q * 4);
        float4 uc = ld4h(u + sc * 32 + q * 4);
        float4 vc = ld4h(v + dc * 32 + q * 4);
        float4 ud = ld4h(u + sd * 32 + q * 4);
        float4 vd = ld4h(v + dd * 32 + q * 4);
        float s0 = fmaxf(ua.x + va.x, 0.f) * w2q.x + fmaxf(ua.y + va.y, 0.f) * w2q.y
                 + fmaxf(ua.z + va.z, 0.f) * w2q.z + fmaxf(ua.w + va.w, 0.f) * w2q.w;
        float s1 = fmaxf(ub.x + vb.x, 0.f) * w2q.x + fmaxf(ub.y + vb.y, 0.f) * w2q.y
                 + fmaxf(ub.z + vb.z, 0.f) * w2q.z + fmaxf(ub.w + vb.w, 0.f) * w2q.w;
        float s2 = fmaxf(uc.x + vc.x, 0.f) * w2q.x + fmaxf(uc.y + vc.y, 0.f) * w2q.y
                 + fmaxf(uc.z + vc.z, 0.f) * w2q.z + fmaxf(uc.w + vc.w, 0.f) * w2q.w;
        float s3 = fmaxf(ud.x + vd.x, 0.f) * w2q.x + fmaxf(ud.y + vd.y, 0.f) * w2q.y
                 + fmaxf(ud.z + vd.z, 0.f) * w2q.z + fmaxf(ud.w + vd.w, 0.f) * w2q.w;
        s0 += __shfl_xor(s0, 1, 8); s0 += __shfl_xor(s0, 2, 8); s0 += __shfl_xor(s0, 4, 8);
        s1 += __shfl_xor(s1, 1, 8); s1 += __shfl_xor(s1, 2, 8); s1 += __shfl_xor(s1, 4, 8);
        s2 += __shfl_xor(s2, 1, 8); s2 += __shfl_xor(s2, 2, 8); s2 += __shfl_xor(s2, 4, 8);
        s3 += __shfl_xor(s3, 1, 8); s3 += __shfl_xor(s3, 2, 8); s3 += __shfl_xor(s3, 4, 8);
        if (q == 0) {
            out[eb] = fmaxf(s0 + mb20, 0.f);
            if (eb + 1 < N_EDGES) out[eb + 1] = fmaxf(s1 + mb20, 0.f);
            if (eb + 2 < N_EDGES) out[eb + 2] = fmaxf(s2 + mb20, 0.f);
            if (eb + 3 < N_EDGES) out[eb + 3] = fmaxf(s3 + mb20, 0.f);
        }
    }
}

// ---------------------------------------------------------------- launch
extern "C" void kernel_launch(void* const* d_in, const int* in_sizes, int n_in,
                              void* d_out, int out_size, void* d_ws, size_t ws_size,
                              hipStream_t stream) {
    const float* x    = (const float*)d_in[0];
    const int*   ei   = (const int*)d_in[1];
    const float* w1   = (const float*)d_in[2];
    const float* as1  = (const float*)d_in[3];
    const float* ad1  = (const float*)d_in[4];
    const float* b1   = (const float*)d_in[5];
    const float* w2   = (const float*)d_in[6];
    const float* as2  = (const float*)d_in[7];
    const float* ad2  = (const float*)d_in[8];
    const float* b2   = (const float*)d_in[9];
    const float* mw1  = (const float*)d_in[10];
    const float* mb1  = (const float*)d_in[11];
    const float* mw2  = (const float*)d_in[12];
    const float* mb2  = (const float*)d_in[13];
    float* out = (float*)d_out;

    const int N = N_NODES;
    // byte-offset workspace layout; p1/h2/u/v 64B-aligned (offsets verified)
    char* base   = (char*)d_ws;
    int* deg     = (int*)(base);                      // N*4
    int* rowptr  = (int*)(base + 400000);             // N*4
    int* cursor  = (int*)(base + 800000);             // N*4
    int* loc     = (int*)(base + 1200000);            // N*4
    int* partial = (int*)(base + 1600000);            // 2048 B
    int* csr_src = (int*)(base + 1602048);            // E*4
    float* p1    = (float*)(base + 8002048);          // 8N*4   (%64==0)
    float* a1d   = (float*)(base + 11202048);         // 4N*4
    float* h2    = (float*)(base + 12802048);         // 32N*4  (%64==0)
    float* a2s   = (float*)(base + 25602048);         // N*4
    float* a2d   = (float*)(base + 26002048);         // N*4
    __half* u    = (__half*)(base + 26402048);        // 32N*2  (%64==0)
    __half* v    = (__half*)(base + 32802048);        // 32N*2  (%64==0)
    float* qv    = (float*)(base + 39202048);         // 24

    const int nb = (N + 255) / 256;

    k_zero_deg<<<nb, 256, 0, stream>>>(deg);
    k_hist_x<<<HISTX_BLOCKS, 256, 0, stream>>>(ei, deg);
    k_scan_part<<<nb, 256, 0, stream>>>(deg, loc, partial);
    k_scan_tot<<<1, 512, 0, stream>>>(partial, nb);
    k_scan_add<<<nb, 256, 0, stream>>>(loc, partial, rowptr, cursor);

    k_scatter_x<<<SCATX_BLOCKS, 256, 0, stream>>>(ei, cursor, csr_src);

    k_q<<<1, 32, 0, stream>>>(w1, as1, ad1, qv);
    k_node1<<<nb, 256, 0, stream>>>(x, qv, a1d, p1);

    k_gat1<<<G1_BLOCKS, 256, 0, stream>>>(rowptr, deg, csr_src, p1, w1, a1d,
                                          b1, w2, as2, ad2, h2, a2s, a2d);

    k_gat2<<<G2_BLOCKS, 256, 0, stream>>>(rowptr, deg, csr_src, h2, a2s, a2d, b2,
                                          mw1, mb1, u, v);

    k_mlp<<<MLP_BLOCKS, 256, 0, stream>>>(ei, u, v, mw2, mb2, out);
}

// Round 15
// 430.968 us; speedup vs baseline: 1.0471x; 1.0444x over previous
//
#include <hip/hip_runtime.h>
#include <hip/hip_fp16.h>
#include <math.h>

#define N_NODES 100000
#define N_EDGES 1600000
#define NEG_SLOPE 0.2f
#define EPS 1e-16f

__device__ __forceinline__ float lrelu(float v) { return v > 0.f ? v : NEG_SLOPE * v; }

// load 4 halfs -> float4 (single 8B load)
__device__ __forceinline__ float4 ld4h(const __half* p) {
    uint2 r = *(const uint2*)p;
    __half2 h0 = *reinterpret_cast<const __half2*>(&r.x);
    __half2 h1 = *reinterpret_cast<const __half2*>(&r.y);
    float2 f0 = __half22float2(h0), f1 = __half22float2(h1);
    return make_float4(f0.x, f0.y, f1.x, f1.y);
}

// ---------------------------------------------------------------- zero deg
__global__ void k_zero_deg(int* __restrict__ deg) {
    int i = blockIdx.x * blockDim.x + threadIdx.x;
    if (i < N_NODES) deg[i] = 0;
}

// ---------------------------------------------------------------- XCD-partitioned histogram of dst
#define HISTX_BLOCKS 2048
__global__ void k_hist_x(const int* __restrict__ ei, int* __restrict__ deg) {
    const int step = (N_NODES + 7) / 8;
    int xcd = blockIdx.x & 7;
    int lo = xcd * step;
    int hi = (lo + step < N_NODES) ? lo + step : N_NODES;
    int gid = (blockIdx.x >> 3) * blockDim.x + threadIdx.x;
    const int stride = (HISTX_BLOCKS >> 3) * 256;
    for (int e = gid; e < N_EDGES; e += stride) {
        int dst = ei[N_EDGES + e];
        if (dst >= lo && dst < hi) atomicAdd(&deg[dst], 1);
    }
}

// ---------------------------------------------------------------- scan level 1
__global__ void k_scan_part(const int* __restrict__ deg, int* __restrict__ loc,
                            int* __restrict__ partial) {
    __shared__ int tmp[256];
    int i = blockIdx.x * 256 + threadIdx.x;
    int v = (i < N_NODES) ? deg[i] : 0;
    tmp[threadIdx.x] = v;
    __syncthreads();
    for (int off = 1; off < 256; off <<= 1) {
        int t = (threadIdx.x >= off) ? tmp[threadIdx.x - off] : 0;
        __syncthreads();
        tmp[threadIdx.x] += t;
        __syncthreads();
    }
    if (i < N_NODES) loc[i] = tmp[threadIdx.x] - v;   // exclusive
    if (threadIdx.x == 255) partial[blockIdx.x] = tmp[255];
}

// ---------------------------------------------------------------- scan level 2 (nb <= 512)
__global__ void k_scan_tot(int* __restrict__ partial, int nb) {
    __shared__ int tmp[512];
    int v = (threadIdx.x < nb) ? partial[threadIdx.x] : 0;
    tmp[threadIdx.x] = v;
    __syncthreads();
    for (int off = 1; off < 512; off <<= 1) {
        int t = (threadIdx.x >= off) ? tmp[threadIdx.x - off] : 0;
        __syncthreads();
        tmp[threadIdx.x] += t;
        __syncthreads();
    }
    if (threadIdx.x < nb) partial[threadIdx.x] = tmp[threadIdx.x] - v;  // exclusive
}

// ---------------------------------------------------------------- scan level 3 + cursor init
__global__ void k_scan_add(const int* __restrict__ loc, const int* __restrict__ partial,
                           int* __restrict__ rowptr, int* __restrict__ cursor) {
    int i = blockIdx.x * blockDim.x + threadIdx.x;
    if (i < N_NODES) {
        int r = loc[i] + partial[i >> 8];
        rowptr[i] = r;
        cursor[i] = r;
    }
}

// ---------------------------------------------------------------- XCD-partitioned scatter
#define SCATX_BLOCKS 2048
__global__ void k_scatter_x(const int* __restrict__ ei, int* __restrict__ cursor,
                            int* __restrict__ csr_src) {
    const int step = (N_NODES + 7) / 8;
    int xcd = blockIdx.x & 7;
    int lo = xcd * step;
    int hi = (lo + step < N_NODES) ? lo + step : N_NODES;
    int gid = (blockIdx.x >> 3) * blockDim.x + threadIdx.x;
    const int stride = (SCATX_BLOCKS >> 3) * 256;
    for (int e = gid; e < N_EDGES; e += stride) {
        int dst = ei[N_EDGES + e];
        if (dst >= lo && dst < hi) {
            int pos = atomicAdd(&cursor[dst], 1);
            csr_src[pos] = ei[e];
        }
    }
}

// ---------------------------------------------------------------- K-Q: qs[h] = W1_h^T a_src_h, qd[h] = W1_h^T a_dst_h  (24 floats)
__global__ void k_q(const float* __restrict__ w1, const float* __restrict__ as1,
                    const float* __restrict__ ad1, float* __restrict__ qv) {
    int t = threadIdx.x;
    if (t >= 24) return;
    int c = t % 3, h = (t / 3) % 4, side = t / 12;
    const float* att = side ? ad1 : as1;
    float acc = 0.f;
    for (int cc = 0; cc < 32; cc++)
        acc += att[h * 32 + cc] * w1[(h * 32 + cc) * 3 + c];
    qv[t] = acc;
}

// ---------------------------------------------------------------- K-NODE1: a1d = x.qd ; p1[n] = {a1s[4], x0,x1,x2,1} (32B row)
__global__ void k_node1(const float* __restrict__ x, const float* __restrict__ qv,
                        float* __restrict__ a1d, float* __restrict__ p1) {
    int n = blockIdx.x * blockDim.x + threadIdx.x;
    if (n >= N_NODES) return;
    float x0 = x[n * 3], x1 = x[n * 3 + 1], x2 = x[n * 3 + 2];
    float4 s, d;
    s.x = x0 * qv[0]  + x1 * qv[1]  + x2 * qv[2];
    s.y = x0 * qv[3]  + x1 * qv[4]  + x2 * qv[5];
    s.z = x0 * qv[6]  + x1 * qv[7]  + x2 * qv[8];
    s.w = x0 * qv[9]  + x1 * qv[10] + x2 * qv[11];
    d.x = x0 * qv[12] + x1 * qv[13] + x2 * qv[14];
    d.y = x0 * qv[15] + x1 * qv[16] + x2 * qv[17];
    d.z = x0 * qv[18] + x1 * qv[19] + x2 * qv[20];
    d.w = x0 * qv[21] + x1 * qv[22] + x2 * qv[23];
    ((float4*)a1d)[n] = d;
    ((float4*)p1)[n * 2]     = s;
    float4 xx; xx.x = x0; xx.y = x1; xx.z = x2; xx.w = 1.f;
    ((float4*)p1)[n * 2 + 1] = xx;
}

// ---------------------------------------------------------------- K-GAT1: linearity trick, w2 in registers, packed p1 gathers
#define G1_BLOCKS ((N_NODES + 63) / 64)
__global__ void k_gat1(const int* __restrict__ rowptr, const int* __restrict__ deg,
                       const int* __restrict__ csr_src,
                       const float* __restrict__ p1, const float* __restrict__ w1,
                       const float* __restrict__ a1d,
                       const float* __restrict__ b1, const float* __restrict__ w2,
                       const float* __restrict__ as2, const float* __restrict__ ad2,
                       float* __restrict__ h2, float* __restrict__ a2s, float* __restrict__ a2d) {
    __shared__ float sm[64][16];      // per-node: 4 heads x {s0,s1,s2,den}
    __shared__ float f1s[4][128];
    int tid = threadIdx.x;
    int wave = tid >> 6, lane = tid & 63;
    int o = lane & 31, half = lane >> 5;
    int k0 = half * 64;

    // per-lane w2 column: w2[o][k0..k0+63] in 64 VGPRs
    float w2r[64];
    {
        const float4* wp = (const float4*)(w2 + o * 128 + k0);
        #pragma unroll
        for (int q = 0; q < 16; q++) {
            float4 t = wp[q];
            w2r[q * 4 + 0] = t.x; w2r[q * 4 + 1] = t.y;
            w2r[q * 4 + 2] = t.z; w2r[q * 4 + 3] = t.w;
        }
    }

    // ---- phase A: node = block*64 + wave*16 + (lane>>2), head = lane&3
    int nl = wave * 16 + (lane >> 2);
    int h  = lane & 3;
    int n  = blockIdx.x * 64 + nl;
    if (n < N_NODES) {
        float adh = a1d[n * 4 + h];
        int beg = rowptr[n], cnt = deg[n];
        float s0a = 0.f, s1a = 0.f, s2a = 0.f, da = 0.f;
        int t = 0;
        for (; t + 4 <= cnt; t += 4) {
            int s0 = csr_src[beg + t + 0], s1 = csr_src[beg + t + 1];
            int s2 = csr_src[beg + t + 2], s3 = csr_src[beg + t + 3];
            float4 A0 = ((const float4*)p1)[s0 * 2], X0 = ((const float4*)p1)[s0 * 2 + 1];
            float4 A1 = ((const float4*)p1)[s1 * 2], X1 = ((const float4*)p1)[s1 * 2 + 1];
            float4 A2 = ((const float4*)p1)[s2 * 2], X2 = ((const float4*)p1)[s2 * 2 + 1];
            float4 A3 = ((const float4*)p1)[s3 * 2], X3 = ((const float4*)p1)[s3 * 2 + 1];
            float l0 = h == 0 ? A0.x : h == 1 ? A0.y : h == 2 ? A0.z : A0.w;
            float l1 = h == 0 ? A1.x : h == 1 ? A1.y : h == 2 ? A1.z : A1.w;
            float l2 = h == 0 ? A2.x : h == 1 ? A2.y : h == 2 ? A2.z : A2.w;
            float l3 = h == 0 ? A3.x : h == 1 ? A3.y : h == 2 ? A3.z : A3.w;
            float e0 = __expf(lrelu(l0 + adh));
            float e1 = __expf(lrelu(l1 + adh));
            float e2 = __expf(lrelu(l2 + adh));
            float e3 = __expf(lrelu(l3 + adh));
            s0a += e0 * X0.x + e1 * X1.x + e2 * X2.x + e3 * X3.x;
            s1a += e0 * X0.y + e1 * X1.y + e2 * X2.y + e3 * X3.y;
            s2a += e0 * X0.z + e1 * X1.z + e2 * X2.z + e3 * X3.z;
            da  += e0 + e1 + e2 + e3;
        }
        for (; t < cnt; t++) {
            int s = csr_src[beg + t];
            float4 A = ((const float4*)p1)[s * 2], X = ((const float4*)p1)[s * 2 + 1];
            float l = h == 0 ? A.x : h == 1 ? A.y : h == 2 ? A.z : A.w;
            float ex = __expf(lrelu(l + adh));
            s0a += ex * X.x;
            s1a += ex * X.y;
            s2a += ex * X.z;
            da  += ex;
        }
        float4 r; r.x = s0a; r.y = s1a; r.z = s2a; r.w = da;
        *(float4*)&sm[nl][h * 4] = r;
    }
    // same-wave LDS write->read below: no barrier needed

    // ---- phase B: wave processes its own 16 nodes
    int j = lane, j2 = lane + 64;
    int h0 = j >> 5;
    float wa0 = w1[j * 3], wa1 = w1[j * 3 + 1], wa2 = w1[j * 3 + 2];
    float wb0 = w1[j2 * 3], wb1 = w1[j2 * 3 + 1], wb2 = w1[j2 * 3 + 2];
    float b1j = b1[j], b1j2 = b1[j2];
    float as2o = as2[o], ad2o = ad2[o];
    const float* f = f1s[wave];

    #pragma unroll 1
    for (int i = 0; i < 16; i++) {
        int n2 = blockIdx.x * 64 + wave * 16 + i;
        if (n2 >= N_NODES) break;
        const float* S = sm[wave * 16 + i];
        float v0 = (wa0 * S[h0 * 4] + wa1 * S[h0 * 4 + 1] + wa2 * S[h0 * 4 + 2])
                   / (S[h0 * 4 + 3] + EPS) + b1j;
        float v1 = (wb0 * S[(2 + h0) * 4] + wb1 * S[(2 + h0) * 4 + 1] + wb2 * S[(2 + h0) * 4 + 2])
                   / (S[(2 + h0) * 4 + 3] + EPS) + b1j2;
        f1s[wave][j]  = v0 > 0.f ? v0 : expm1f(v0);
        f1s[wave][j2] = v1 > 0.f ? v1 : expm1f(v1);
        float acc = 0.f;
        #pragma unroll
        for (int t = 0; t < 64; t++)
            acc += f[k0 + t] * w2r[t];
        acc += __shfl_down(acc, 32);
        if (half == 0) {
            h2[n2 * 32 + o] = acc;
            float ps = acc * as2o, pd = acc * ad2o;
            #pragma unroll
            for (int off = 16; off; off >>= 1) {
                ps += __shfl_xor(ps, off);
                pd += __shfl_xor(pd, off);
            }
            if (o == 0) { a2s[n2] = ps; a2d[n2] = pd; }
        }
    }
}

// ---------------------------------------------------------------- K-GAT2: edge-broadcast + unroll-4 + LDS weights
// wave per node. Lane l owns edge (base+l): coalesced csr load, 1 gather +
// 1 expf per edge. Broadcast loop unrolled x4 per half -> 4 h2 rows in
// flight per VMEM instr (both halves share the instruction). mw1 in padded
// LDS (stride 33: banks (c+k)%32, 2-way across halves = free) keeps VGPR low.
#define G2_BLOCKS 4096
__global__ void k_gat2(const int* __restrict__ rowptr, const int* __restrict__ deg,
                       const int* __restrict__ csr_src,
                       const float* __restrict__ h2, const float* __restrict__ a2s,
                       const float* __restrict__ a2d, const float* __restrict__ b2,
                       const float* __restrict__ mw1, const float* __restrict__ mb1,
                       __half* __restrict__ u, __half* __restrict__ v) {
    __shared__ float Ws[2][32 * 33];     // [half][c*33+k]
    int tid = threadIdx.x;
    for (int i = tid; i < 2048; i += 256) {
        int c = i >> 6, k = i & 63;
        Ws[k >> 5][c * 33 + (k & 31)] = mw1[i];
    }
    __syncthreads();
    int lane = tid & 63;
    int c = lane & 31, half = lane >> 5;
    const float* W = Ws[half] + c * 33;
    float bias = half ? 0.f : mb1[c];
    float b2c = b2[c];
    __half* outp = half ? v : u;
    int wid = blockIdx.x * 4 + (tid >> 6);
    const int stride = G2_BLOCKS * 4;
    for (int n = wid; n < N_NODES; n += stride) {
        float ad = a2d[n];
        int beg = rowptr[n], cnt = deg[n];
        float acc = 0.f, den = 0.f;
        for (int base = 0; base < cnt; base += 64) {
            int li = base + lane;
            int idx = (li < cnt) ? csr_src[beg + li] : 0;   // coalesced
            float e = 0.f;
            if (li < cnt) e = __expf(lrelu(a2s[idx] + ad)); // 1 gather+expf per edge
            den += e;
            int m = cnt - base; if (m > 64) m = 64;
            int t = half;
            for (; t + 6 < m; t += 8) {      // 4 edges per half, 4 loads in flight
                int   s0 = __shfl(idx, t),     s1 = __shfl(idx, t + 2);
                int   s2 = __shfl(idx, t + 4), s3 = __shfl(idx, t + 6);
                float e0 = __shfl(e, t),       e1 = __shfl(e, t + 2);
                float e2 = __shfl(e, t + 4),   e3 = __shfl(e, t + 6);
                float g0 = h2[s0 * 32 + c], g1 = h2[s1 * 32 + c];
                float g2 = h2[s2 * 32 + c], g3 = h2[s3 * 32 + c];
                acc += e0 * g0 + e1 * g1 + e2 * g2 + e3 * g3;
            }
            for (; t + 2 < m; t += 4) {      // pair remainder
                int   s0 = __shfl(idx, t), s1 = __shfl(idx, t + 2);
                float e0 = __shfl(e, t),   e1 = __shfl(e, t + 2);
                acc += e0 * h2[s0 * 32 + c] + e1 * h2[s1 * 32 + c];
            }
            if (t < m) {
                int   s0 = __shfl(idx, t);
                float e0 = __shfl(e, t);
                acc += e0 * h2[s0 * 32 + c];
            }
        }
        acc += __shfl_xor(acc, 32);          // combine halves (channel c total)
        #pragma unroll
        for (int off = 32; off; off >>= 1) den += __shfl_xor(den, off);
        float hfc = acc / (den + EPS) + b2c;
        float r = bias;
        #pragma unroll
        for (int k = 0; k < 32; k++)
            r += W[k] * __shfl(hfc, k, 32);
        outp[n * 32 + c] = __float2half(r);
    }
}

// ---------------------------------------------------------------- K-MLP: 8 lanes/edge, 4 edges/iter, fp16 u/v rows (1 line each)
#define MLP_BLOCKS 4096
__global__ void k_mlp(const int* __restrict__ ei, const __half* __restrict__ u,
                      const __half* __restrict__ v, const float* __restrict__ mw2,
                      const float* __restrict__ mb2, float* __restrict__ out) {
    int tid = threadIdx.x;
    int q = tid & 7;
    float4 w2q = ((const float4*)mw2)[q];
    float mb20 = mb2[0];
    int g = blockIdx.x * 32 + (tid >> 3);
    const int stride = MLP_BLOCKS * 32 * 4;
    for (int e = g * 4; e < N_EDGES; e += stride) {
        int eb = e;
        int e1 = (eb + 1 < N_EDGES) ? eb + 1 : eb;
        int e2 = (eb + 2 < N_EDGES) ? eb + 2 : eb;
        int e3 = (eb + 3 < N_EDGES) ? eb + 3 : eb;
        int sa = ei[eb], da = ei[N_EDGES + eb];
        int sb = ei[e1], db = ei[N_EDGES + e1];
        int sc = ei[e2], dc = ei[N_EDGES + e2];
        int sd = ei[e3], dd = ei[N_EDGES + e3];
        float4 ua = ld4h(u + sa * 32 + q * 4);
        float4 va = ld4h(v + da * 32 + q * 4);
        float4 ub = ld4h(u + sb * 32 + q * 4);
        float4 vb = ld4h(v + db * 32 + q * 4);
        float4 uc = ld4h(u + sc * 32 + q * 4);
        float4 vc = ld4h(v + dc * 32 + q * 4);
        float4 ud = ld4h(u + sd * 32 + q * 4);
        float4 vd = ld4h(v + dd * 32 + q * 4);
        float s0 = fmaxf(ua.x + va.x, 0.f) * w2q.x + fmaxf(ua.y + va.y, 0.f) * w2q.y
                 + fmaxf(ua.z + va.z, 0.f) * w2q.z + fmaxf(ua.w + va.w, 0.f) * w2q.w;
        float s1 = fmaxf(ub.x + vb.x, 0.f) * w2q.x + fmaxf(ub.y + vb.y, 0.f) * w2q.y
                 + fmaxf(ub.z + vb.z, 0.f) * w2q.z + fmaxf(ub.w + vb.w, 0.f) * w2q.w;
        float s2 = fmaxf(uc.x + vc.x, 0.f) * w2q.x + fmaxf(uc.y + vc.y, 0.f) * w2q.y
                 + fmaxf(uc.z + vc.z, 0.f) * w2q.z + fmaxf(uc.w + vc.w, 0.f) * w2q.w;
        float s3 = fmaxf(ud.x + vd.x, 0.f) * w2q.x + fmaxf(ud.y + vd.y, 0.f) * w2q.y
                 + fmaxf(ud.z + vd.z, 0.f) * w2q.z + fmaxf(ud.w + vd.w, 0.f) * w2q.w;
        s0 += __shfl_xor(s0, 1, 8); s0 += __shfl_xor(s0, 2, 8); s0 += __shfl_xor(s0, 4, 8);
        s1 += __shfl_xor(s1, 1, 8); s1 += __shfl_xor(s1, 2, 8); s1 += __shfl_xor(s1, 4, 8);
        s2 += __shfl_xor(s2, 1, 8); s2 += __shfl_xor(s2, 2, 8); s2 += __shfl_xor(s2, 4, 8);
        s3 += __shfl_xor(s3, 1, 8); s3 += __shfl_xor(s3, 2, 8); s3 += __shfl_xor(s3, 4, 8);
        if (q == 0) {
            out[eb] = fmaxf(s0 + mb20, 0.f);
            if (eb + 1 < N_EDGES) out[eb + 1] = fmaxf(s1 + mb20, 0.f);
            if (eb + 2 < N_EDGES) out[eb + 2] = fmaxf(s2 + mb20, 0.f);
            if (eb + 3 < N_EDGES) out[eb + 3] = fmaxf(s3 + mb20, 0.f);
        }
    }
}

// ---------------------------------------------------------------- launch
extern "C" void kernel_launch(void* const* d_in, const int* in_sizes, int n_in,
                              void* d_out, int out_size, void* d_ws, size_t ws_size,
                              hipStream_t stream) {
    const float* x    = (const float*)d_in[0];
    const int*   ei   = (const int*)d_in[1];
    const float* w1   = (const float*)d_in[2];
    const float* as1  = (const float*)d_in[3];
    const float* ad1  = (const float*)d_in[4];
    const float* b1   = (const float*)d_in[5];
    const float* w2   = (const float*)d_in[6];
    const float* as2  = (const float*)d_in[7];
    const float* ad2  = (const float*)d_in[8];
    const float* b2   = (const float*)d_in[9];
    const float* mw1  = (const float*)d_in[10];
    const float* mb1  = (const float*)d_in[11];
    const float* mw2  = (const float*)d_in[12];
    const float* mb2  = (const float*)d_in[13];
    float* out = (float*)d_out;

    const int N = N_NODES;
    // byte-offset workspace layout; p1/h2/u/v 64B-aligned (offsets verified)
    char* base   = (char*)d_ws;
    int* deg     = (int*)(base);                      // N*4
    int* rowptr  = (int*)(base + 400000);             // N*4
    int* cursor  = (int*)(base + 800000);             // N*4
    int* loc     = (int*)(base + 1200000);            // N*4
    int* partial = (int*)(base + 1600000);            // 2048 B
    int* csr_src = (int*)(base + 1602048);            // E*4
    float* p1    = (float*)(base + 8002048);          // 8N*4   (%64==0)
    float* a1d   = (float*)(base + 11202048);         // 4N*4
    float* h2    = (float*)(base + 12802048);         // 32N*4  (%64==0)
    float* a2s   = (float*)(base + 25602048);         // N*4
    float* a2d   = (float*)(base + 26002048);         // N*4
    __half* u    = (__half*)(base + 26402048);        // 32N*2  (%64==0)
    __half* v    = (__half*)(base + 32802048);        // 32N*2  (%64==0)
    float* qv    = (float*)(base + 39202048);         // 24

    const int nb = (N + 255) / 256;

    k_zero_deg<<<nb, 256, 0, stream>>>(deg);
    k_hist_x<<<HISTX_BLOCKS, 256, 0, stream>>>(ei, deg);
    k_scan_part<<<nb, 256, 0, stream>>>(deg, loc, partial);
    k_scan_tot<<<1, 512, 0, stream>>>(partial, nb);
    k_scan_add<<<nb, 256, 0, stream>>>(loc, partial, rowptr, cursor);

    k_scatter_x<<<SCATX_BLOCKS, 256, 0, stream>>>(ei, cursor, csr_src);

    k_q<<<1, 32, 0, stream>>>(w1, as1, ad1, qv);
    k_node1<<<nb, 256, 0, stream>>>(x, qv, a1d, p1);

    k_gat1<<<G1_BLOCKS, 256, 0, stream>>>(rowptr, deg, csr_src, p1, w1, a1d,
                                          b1, w2, as2, ad2, h2, a2s, a2d);

    k_gat2<<<G2_BLOCKS, 256, 0, stream>>>(rowptr, deg, csr_src, h2, a2s, a2d, b2,
                                          mw1, mb1, u, v);

    k_mlp<<<MLP_BLOCKS, 256, 0, stream>>>(ei, u, v, mw2, mb2, out);
}

// Round 16
// 409.798 us; speedup vs baseline: 1.1012x; 1.0517x over previous
//
#include <hip/hip_runtime.h>
#include <hip/hip_fp16.h>
#include <math.h>

#define N_NODES 100000
#define N_EDGES 1600000
#define NEG_SLOPE 0.2f
#define EPS 1e-16f

__device__ __forceinline__ float lrelu(float v) { return v > 0.f ? v : NEG_SLOPE * v; }

// load 4 halfs -> float4 (single 8B load)
__device__ __forceinline__ float4 ld4h(const __half* p) {
    uint2 r = *(const uint2*)p;
    __half2 h0 = *reinterpret_cast<const __half2*>(&r.x);
    __half2 h1 = *reinterpret_cast<const __half2*>(&r.y);
    float2 f0 = __half22float2(h0), f1 = __half22float2(h1);
    return make_float4(f0.x, f0.y, f1.x, f1.y);
}

// ---------------------------------------------------------------- zero deg
__global__ void k_zero_deg(int* __restrict__ deg) {
    int i = blockIdx.x * blockDim.x + threadIdx.x;
    if (i < N_NODES) deg[i] = 0;
}

// ---------------------------------------------------------------- XCD-partitioned histogram of dst
#define HISTX_BLOCKS 2048
__global__ void k_hist_x(const int* __restrict__ ei, int* __restrict__ deg) {
    const int step = (N_NODES + 7) / 8;
    int xcd = blockIdx.x & 7;
    int lo = xcd * step;
    int hi = (lo + step < N_NODES) ? lo + step : N_NODES;
    int gid = (blockIdx.x >> 3) * blockDim.x + threadIdx.x;
    const int stride = (HISTX_BLOCKS >> 3) * 256;
    for (int e = gid; e < N_EDGES; e += stride) {
        int dst = ei[N_EDGES + e];
        if (dst >= lo && dst < hi) atomicAdd(&deg[dst], 1);
    }
}

// ---------------------------------------------------------------- scan level 1
__global__ void k_scan_part(const int* __restrict__ deg, int* __restrict__ loc,
                            int* __restrict__ partial) {
    __shared__ int tmp[256];
    int i = blockIdx.x * 256 + threadIdx.x;
    int v = (i < N_NODES) ? deg[i] : 0;
    tmp[threadIdx.x] = v;
    __syncthreads();
    for (int off = 1; off < 256; off <<= 1) {
        int t = (threadIdx.x >= off) ? tmp[threadIdx.x - off] : 0;
        __syncthreads();
        tmp[threadIdx.x] += t;
        __syncthreads();
    }
    if (i < N_NODES) loc[i] = tmp[threadIdx.x] - v;   // exclusive
    if (threadIdx.x == 255) partial[blockIdx.x] = tmp[255];
}

// ---------------------------------------------------------------- scan level 2 (nb <= 512)
__global__ void k_scan_tot(int* __restrict__ partial, int nb) {
    __shared__ int tmp[512];
    int v = (threadIdx.x < nb) ? partial[threadIdx.x] : 0;
    tmp[threadIdx.x] = v;
    __syncthreads();
    for (int off = 1; off < 512; off <<= 1) {
        int t = (threadIdx.x >= off) ? tmp[threadIdx.x - off] : 0;
        __syncthreads();
        tmp[threadIdx.x] += t;
        __syncthreads();
    }
    if (threadIdx.x < nb) partial[threadIdx.x] = tmp[threadIdx.x] - v;  // exclusive
}

// ---------------------------------------------------------------- scan level 3 + cursor init
__global__ void k_scan_add(const int* __restrict__ loc, const int* __restrict__ partial,
                           int* __restrict__ rowptr, int* __restrict__ cursor) {
    int i = blockIdx.x * blockDim.x + threadIdx.x;
    if (i < N_NODES) {
        int r = loc[i] + partial[i >> 8];
        rowptr[i] = r;
        cursor[i] = r;
    }
}

// ---------------------------------------------------------------- XCD-partitioned scatter
#define SCATX_BLOCKS 2048
__global__ void k_scatter_x(const int* __restrict__ ei, int* __restrict__ cursor,
                            int* __restrict__ csr_src) {
    const int step = (N_NODES + 7) / 8;
    int xcd = blockIdx.x & 7;
    int lo = xcd * step;
    int hi = (lo + step < N_NODES) ? lo + step : N_NODES;
    int gid = (blockIdx.x >> 3) * blockDim.x + threadIdx.x;
    const int stride = (SCATX_BLOCKS >> 3) * 256;
    for (int e = gid; e < N_EDGES; e += stride) {
        int dst = ei[N_EDGES + e];
        if (dst >= lo && dst < hi) {
            int pos = atomicAdd(&cursor[dst], 1);
            csr_src[pos] = ei[e];
        }
    }
}

// ---------------------------------------------------------------- K-Q: qs[h] = W1_h^T a_src_h, qd[h] = W1_h^T a_dst_h  (24 floats)
__global__ void k_q(const float* __restrict__ w1, const float* __restrict__ as1,
                    const float* __restrict__ ad1, float* __restrict__ qv) {
    int t = threadIdx.x;
    if (t >= 24) return;
    int c = t % 3, h = (t / 3) % 4, side = t / 12;
    const float* att = side ? ad1 : as1;
    float acc = 0.f;
    for (int cc = 0; cc < 32; cc++)
        acc += att[h * 32 + cc] * w1[(h * 32 + cc) * 3 + c];
    qv[t] = acc;
}

// ---------------------------------------------------------------- K-NODE1: a1d = x.qd ; p1[n] = {a1s[4], x0,x1,x2,1} (32B row)
__global__ void k_node1(const float* __restrict__ x, const float* __restrict__ qv,
                        float* __restrict__ a1d, float* __restrict__ p1) {
    int n = blockIdx.x * blockDim.x + threadIdx.x;
    if (n >= N_NODES) return;
    float x0 = x[n * 3], x1 = x[n * 3 + 1], x2 = x[n * 3 + 2];
    float4 s, d;
    s.x = x0 * qv[0]  + x1 * qv[1]  + x2 * qv[2];
    s.y = x0 * qv[3]  + x1 * qv[4]  + x2 * qv[5];
    s.z = x0 * qv[6]  + x1 * qv[7]  + x2 * qv[8];
    s.w = x0 * qv[9]  + x1 * qv[10] + x2 * qv[11];
    d.x = x0 * qv[12] + x1 * qv[13] + x2 * qv[14];
    d.y = x0 * qv[15] + x1 * qv[16] + x2 * qv[17];
    d.z = x0 * qv[18] + x1 * qv[19] + x2 * qv[20];
    d.w = x0 * qv[21] + x1 * qv[22] + x2 * qv[23];
    ((float4*)a1d)[n] = d;
    ((float4*)p1)[n * 2]     = s;
    float4 xx; xx.x = x0; xx.y = x1; xx.z = x2; xx.w = 1.f;
    ((float4*)p1)[n * 2 + 1] = xx;
}

// ---------------------------------------------------------------- K-GAT1: linearity trick, w2 in registers, packed p1 gathers
#define G1_BLOCKS ((N_NODES + 63) / 64)
__global__ void k_gat1(const int* __restrict__ rowptr, const int* __restrict__ deg,
                       const int* __restrict__ csr_src,
                       const float* __restrict__ p1, const float* __restrict__ w1,
                       const float* __restrict__ a1d,
                       const float* __restrict__ b1, const float* __restrict__ w2,
                       const float* __restrict__ as2, const float* __restrict__ ad2,
                       float* __restrict__ h2, float* __restrict__ a2s, float* __restrict__ a2d) {
    __shared__ float sm[64][16];      // per-node: 4 heads x {s0,s1,s2,den}
    __shared__ float f1s[4][128];
    int tid = threadIdx.x;
    int wave = tid >> 6, lane = tid & 63;
    int o = lane & 31, half = lane >> 5;
    int k0 = half * 64;

    // per-lane w2 column: w2[o][k0..k0+63] in 64 VGPRs
    float w2r[64];
    {
        const float4* wp = (const float4*)(w2 + o * 128 + k0);
        #pragma unroll
        for (int q = 0; q < 16; q++) {
            float4 t = wp[q];
            w2r[q * 4 + 0] = t.x; w2r[q * 4 + 1] = t.y;
            w2r[q * 4 + 2] = t.z; w2r[q * 4 + 3] = t.w;
        }
    }

    // ---- phase A: node = block*64 + wave*16 + (lane>>2), head = lane&3
    int nl = wave * 16 + (lane >> 2);
    int h  = lane & 3;
    int n  = blockIdx.x * 64 + nl;
    if (n < N_NODES) {
        float adh = a1d[n * 4 + h];
        int beg = rowptr[n], cnt = deg[n];
        float s0a = 0.f, s1a = 0.f, s2a = 0.f, da = 0.f;
        int t = 0;
        for (; t + 4 <= cnt; t += 4) {
            int s0 = csr_src[beg + t + 0], s1 = csr_src[beg + t + 1];
            int s2 = csr_src[beg + t + 2], s3 = csr_src[beg + t + 3];
            float4 A0 = ((const float4*)p1)[s0 * 2], X0 = ((const float4*)p1)[s0 * 2 + 1];
            float4 A1 = ((const float4*)p1)[s1 * 2], X1 = ((const float4*)p1)[s1 * 2 + 1];
            float4 A2 = ((const float4*)p1)[s2 * 2], X2 = ((const float4*)p1)[s2 * 2 + 1];
            float4 A3 = ((const float4*)p1)[s3 * 2], X3 = ((const float4*)p1)[s3 * 2 + 1];
            float l0 = h == 0 ? A0.x : h == 1 ? A0.y : h == 2 ? A0.z : A0.w;
            float l1 = h == 0 ? A1.x : h == 1 ? A1.y : h == 2 ? A1.z : A1.w;
            float l2 = h == 0 ? A2.x : h == 1 ? A2.y : h == 2 ? A2.z : A2.w;
            float l3 = h == 0 ? A3.x : h == 1 ? A3.y : h == 2 ? A3.z : A3.w;
            float e0 = __expf(lrelu(l0 + adh));
            float e1 = __expf(lrelu(l1 + adh));
            float e2 = __expf(lrelu(l2 + adh));
            float e3 = __expf(lrelu(l3 + adh));
            s0a += e0 * X0.x + e1 * X1.x + e2 * X2.x + e3 * X3.x;
            s1a += e0 * X0.y + e1 * X1.y + e2 * X2.y + e3 * X3.y;
            s2a += e0 * X0.z + e1 * X1.z + e2 * X2.z + e3 * X3.z;
            da  += e0 + e1 + e2 + e3;
        }
        for (; t < cnt; t++) {
            int s = csr_src[beg + t];
            float4 A = ((const float4*)p1)[s * 2], X = ((const float4*)p1)[s * 2 + 1];
            float l = h == 0 ? A.x : h == 1 ? A.y : h == 2 ? A.z : A.w;
            float ex = __expf(lrelu(l + adh));
            s0a += ex * X.x;
            s1a += ex * X.y;
            s2a += ex * X.z;
            da  += ex;
        }
        float4 r; r.x = s0a; r.y = s1a; r.z = s2a; r.w = da;
        *(float4*)&sm[nl][h * 4] = r;
    }
    // same-wave LDS write->read below: no barrier needed

    // ---- phase B: wave processes its own 16 nodes
    int j = lane, j2 = lane + 64;
    int h0 = j >> 5;
    float wa0 = w1[j * 3], wa1 = w1[j * 3 + 1], wa2 = w1[j * 3 + 2];
    float wb0 = w1[j2 * 3], wb1 = w1[j2 * 3 + 1], wb2 = w1[j2 * 3 + 2];
    float b1j = b1[j], b1j2 = b1[j2];
    float as2o = as2[o], ad2o = ad2[o];
    const float* f = f1s[wave];

    #pragma unroll 1
    for (int i = 0; i < 16; i++) {
        int n2 = blockIdx.x * 64 + wave * 16 + i;
        if (n2 >= N_NODES) break;
        const float* S = sm[wave * 16 + i];
        float v0 = (wa0 * S[h0 * 4] + wa1 * S[h0 * 4 + 1] + wa2 * S[h0 * 4 + 2])
                   / (S[h0 * 4 + 3] + EPS) + b1j;
        float v1 = (wb0 * S[(2 + h0) * 4] + wb1 * S[(2 + h0) * 4 + 1] + wb2 * S[(2 + h0) * 4 + 2])
                   / (S[(2 + h0) * 4 + 3] + EPS) + b1j2;
        f1s[wave][j]  = v0 > 0.f ? v0 : expm1f(v0);
        f1s[wave][j2] = v1 > 0.f ? v1 : expm1f(v1);
        float acc = 0.f;
        #pragma unroll
        for (int t = 0; t < 64; t++)
            acc += f[k0 + t] * w2r[t];
        acc += __shfl_down(acc, 32);
        if (half == 0) {
            h2[n2 * 32 + o] = acc;
            float ps = acc * as2o, pd = acc * ad2o;
            #pragma unroll
            for (int off = 16; off; off >>= 1) {
                ps += __shfl_xor(ps, off);
                pd += __shfl_xor(pd, off);
            }
            if (o == 0) { a2s[n2] = ps; a2d[n2] = pd; }
        }
    }
}

// ---------------------------------------------------------------- K-GAT2: edge-broadcast via LDS staging (low LDS-pipe-op count)
// wave per node. Lane l owns edge (base+l): coalesced csr load, 1 gather +
// 1 expf per edge; (idx,e) staged in LDS as int2 -> 1 broadcast ds_read_b64
// per edge (replaces 2 bpermutes). Epilogue matvec: hf staged once, W rows
// read as 8x ds_read_b128 (pad 36 -> 16B-aligned, 4-way banks ~1.6x).
#define G2_BLOCKS 4096
__global__ void k_gat2(const int* __restrict__ rowptr, const int* __restrict__ deg,
                       const int* __restrict__ csr_src,
                       const float* __restrict__ h2, const float* __restrict__ a2s,
                       const float* __restrict__ a2d, const float* __restrict__ b2,
                       const float* __restrict__ mw1, const float* __restrict__ mb1,
                       __half* __restrict__ u, __half* __restrict__ v) {
    __shared__ float Ws2[2][32 * 36];    // [half][c*36+k]; row start 144B (16B-aligned)
    __shared__ int2  pk[4][64];          // per-wave staged (idx, e-bits)
    __shared__ float4 hfs[4][8];         // per-wave hf vector (32 floats)
    int tid = threadIdx.x;
    for (int i = tid; i < 2048; i += 256) {
        int c = i >> 6, col = i & 63;
        Ws2[col >> 5][c * 36 + (col & 31)] = mw1[i];
    }
    __syncthreads();
    int lane = tid & 63, w = tid >> 6;
    int c = lane & 31, half = lane >> 5;
    float bias = half ? 0.f : mb1[c];
    float b2c = b2[c];
    __half* outp = half ? v : u;
    const float4* Wr = (const float4*)&Ws2[half][c * 36];
    int wid = blockIdx.x * 4 + w;
    const int stride = G2_BLOCKS * 4;
    for (int n = wid; n < N_NODES; n += stride) {
        float ad = a2d[n];
        int beg = rowptr[n], cnt = deg[n];
        float acc = 0.f, den = 0.f;
        for (int base = 0; base < cnt; base += 64) {
            int li = base + lane;
            int idx = (li < cnt) ? csr_src[beg + li] : 0;   // coalesced
            float e = 0.f;
            if (li < cnt) e = __expf(lrelu(a2s[idx] + ad)); // 1 gather+expf per edge
            den += e;
            pk[w][lane] = make_int2(idx, __float_as_int(e)); // same-wave stage
            int m = cnt - base; if (m > 64) m = 64;
            int t = half;
            for (; t + 6 < m; t += 8) {      // 4 edges/half, 4 h2 loads in flight
                int2 p0 = pk[w][t],     p1 = pk[w][t + 2];
                int2 p2 = pk[w][t + 4], p3 = pk[w][t + 6];
                float g0 = h2[p0.x * 32 + c], g1 = h2[p1.x * 32 + c];
                float g2 = h2[p2.x * 32 + c], g3 = h2[p3.x * 32 + c];
                acc += __int_as_float(p0.y) * g0 + __int_as_float(p1.y) * g1
                     + __int_as_float(p2.y) * g2 + __int_as_float(p3.y) * g3;
            }
            for (; t + 2 < m; t += 4) {
                int2 p0 = pk[w][t], p1 = pk[w][t + 2];
                acc += __int_as_float(p0.y) * h2[p0.x * 32 + c]
                     + __int_as_float(p1.y) * h2[p1.x * 32 + c];
            }
            if (t < m) {
                int2 p0 = pk[w][t];
                acc += __int_as_float(p0.y) * h2[p0.x * 32 + c];
            }
        }
        acc += __shfl_xor(acc, 32);          // combine halves (channel c total)
        #pragma unroll
        for (int off = 32; off; off >>= 1) den += __shfl_xor(den, off);
        float hfc = acc / (den + EPS) + b2c;
        if (half == 0) ((float*)hfs[w])[c] = hfc;   // same-wave stage
        float r = bias;
        #pragma unroll
        for (int q = 0; q < 8; q++) {
            float4 Wq = Wr[q];               // 4-way bank (~1.6x), 8 ops
            float4 hq = hfs[w][q];           // wave-uniform broadcast, free
            r += Wq.x * hq.x + Wq.y * hq.y + Wq.z * hq.z + Wq.w * hq.w;
        }
        outp[n * 32 + c] = __float2half(r);
    }
}

// ---------------------------------------------------------------- K-MLP: 8 lanes/edge, 4 edges/iter, fp16 u/v rows (1 line each)
#define MLP_BLOCKS 4096
__global__ void k_mlp(const int* __restrict__ ei, const __half* __restrict__ u,
                      const __half* __restrict__ v, const float* __restrict__ mw2,
                      const float* __restrict__ mb2, float* __restrict__ out) {
    int tid = threadIdx.x;
    int q = tid & 7;
    float4 w2q = ((const float4*)mw2)[q];
    float mb20 = mb2[0];
    int g = blockIdx.x * 32 + (tid >> 3);
    const int stride = MLP_BLOCKS * 32 * 4;
    for (int e = g * 4; e < N_EDGES; e += stride) {
        int eb = e;
        int e1 = (eb + 1 < N_EDGES) ? eb + 1 : eb;
        int e2 = (eb + 2 < N_EDGES) ? eb + 2 : eb;
        int e3 = (eb + 3 < N_EDGES) ? eb + 3 : eb;
        int sa = ei[eb], da = ei[N_EDGES + eb];
        int sb = ei[e1], db = ei[N_EDGES + e1];
        int sc = ei[e2], dc = ei[N_EDGES + e2];
        int sd = ei[e3], dd = ei[N_EDGES + e3];
        float4 ua = ld4h(u + sa * 32 + q * 4);
        float4 va = ld4h(v + da * 32 + q * 4);
        float4 ub = ld4h(u + sb * 32 + q * 4);
        float4 vb = ld4h(v + db * 32 + q * 4);
        float4 uc = ld4h(u + sc * 32 + q * 4);
        float4 vc = ld4h(v + dc * 32 + q * 4);
        float4 ud = ld4h(u + sd * 32 + q * 4);
        float4 vd = ld4h(v + dd * 32 + q * 4);
        float s0 = fmaxf(ua.x + va.x, 0.f) * w2q.x + fmaxf(ua.y + va.y, 0.f) * w2q.y
                 + fmaxf(ua.z + va.z, 0.f) * w2q.z + fmaxf(ua.w + va.w, 0.f) * w2q.w;
        float s1 = fmaxf(ub.x + vb.x, 0.f) * w2q.x + fmaxf(ub.y + vb.y, 0.f) * w2q.y
                 + fmaxf(ub.z + vb.z, 0.f) * w2q.z + fmaxf(ub.w + vb.w, 0.f) * w2q.w;
        float s2 = fmaxf(uc.x + vc.x, 0.f) * w2q.x + fmaxf(uc.y + vc.y, 0.f) * w2q.y
                 + fmaxf(uc.z + vc.z, 0.f) * w2q.z + fmaxf(uc.w + vc.w, 0.f) * w2q.w;
        float s3 = fmaxf(ud.x + vd.x, 0.f) * w2q.x + fmaxf(ud.y + vd.y, 0.f) * w2q.y
                 + fmaxf(ud.z + vd.z, 0.f) * w2q.z + fmaxf(ud.w + vd.w, 0.f) * w2q.w;
        s0 += __shfl_xor(s0, 1, 8); s0 += __shfl_xor(s0, 2, 8); s0 += __shfl_xor(s0, 4, 8);
        s1 += __shfl_xor(s1, 1, 8); s1 += __shfl_xor(s1, 2, 8); s1 += __shfl_xor(s1, 4, 8);
        s2 += __shfl_xor(s2, 1, 8); s2 += __shfl_xor(s2, 2, 8); s2 += __shfl_xor(s2, 4, 8);
        s3 += __shfl_xor(s3, 1, 8); s3 += __shfl_xor(s3, 2, 8); s3 += __shfl_xor(s3, 4, 8);
        if (q == 0) {
            out[eb] = fmaxf(s0 + mb20, 0.f);
            if (eb + 1 < N_EDGES) out[eb + 1] = fmaxf(s1 + mb20, 0.f);
            if (eb + 2 < N_EDGES) out[eb + 2] = fmaxf(s2 + mb20, 0.f);
            if (eb + 3 < N_EDGES) out[eb + 3] = fmaxf(s3 + mb20, 0.f);
        }
    }
}

// ---------------------------------------------------------------- launch
extern "C" void kernel_launch(void* const* d_in, const int* in_sizes, int n_in,
                              void* d_out, int out_size, void* d_ws, size_t ws_size,
                              hipStream_t stream) {
    const float* x    = (const float*)d_in[0];
    const int*   ei   = (const int*)d_in[1];
    const float* w1   = (const float*)d_in[2];
    const float* as1  = (const float*)d_in[3];
    const float* ad1  = (const float*)d_in[4];
    const float* b1   = (const float*)d_in[5];
    const float* w2   = (const float*)d_in[6];
    const float* as2  = (const float*)d_in[7];
    const float* ad2  = (const float*)d_in[8];
    const float* b2   = (const float*)d_in[9];
    const float* mw1  = (const float*)d_in[10];
    const float* mb1  = (const float*)d_in[11];
    const float* mw2  = (const float*)d_in[12];
    const float* mb2  = (const float*)d_in[13];
    float* out = (float*)d_out;

    const int N = N_NODES;
    // byte-offset workspace layout; p1/h2/u/v 64B-aligned (offsets verified)
    char* base   = (char*)d_ws;
    int* deg     = (int*)(base);                      // N*4
    int* rowptr  = (int*)(base + 400000);             // N*4
    int* cursor  = (int*)(base + 800000);             // N*4
    int* loc     = (int*)(base + 1200000);            // N*4
    int* partial = (int*)(base + 1600000);            // 2048 B
    int* csr_src = (int*)(base + 1602048);            // E*4
    float* p1    = (float*)(base + 8002048);          // 8N*4   (%64==0)
    float* a1d   = (float*)(base + 11202048);         // 4N*4
    float* h2    = (float*)(base + 12802048);         // 32N*4  (%64==0)
    float* a2s   = (float*)(base + 25602048);         // N*4
    float* a2d   = (float*)(base + 26002048);         // N*4
    __half* u    = (__half*)(base + 26402048);        // 32N*2  (%64==0)
    __half* v    = (__half*)(base + 32802048);        // 32N*2  (%64==0)
    float* qv    = (float*)(base + 39202048);         // 24

    const int nb = (N + 255) / 256;

    k_zero_deg<<<nb, 256, 0, stream>>>(deg);
    k_hist_x<<<HISTX_BLOCKS, 256, 0, stream>>>(ei, deg);
    k_scan_part<<<nb, 256, 0, stream>>>(deg, loc, partial);
    k_scan_tot<<<1, 512, 0, stream>>>(partial, nb);
    k_scan_add<<<nb, 256, 0, stream>>>(loc, partial, rowptr, cursor);

    k_scatter_x<<<SCATX_BLOCKS, 256, 0, stream>>>(ei, cursor, csr_src);

    k_q<<<1, 32, 0, stream>>>(w1, as1, ad1, qv);
    k_node1<<<nb, 256, 0, stream>>>(x, qv, a1d, p1);

    k_gat1<<<G1_BLOCKS, 256, 0, stream>>>(rowptr, deg, csr_src, p1, w1, a1d,
                                          b1, w2, as2, ad2, h2, a2s, a2d);

    k_gat2<<<G2_BLOCKS, 256, 0, stream>>>(rowptr, deg, csr_src, h2, a2s, a2d, b2,
                                          mw1, mb1, u, v);

    k_mlp<<<MLP_BLOCKS, 256, 0, stream>>>(ei, u, v, mw2, mb2, out);
}